// Round 2
// baseline (4812.347 us; speedup 1.0000x reference)
//
#include <hip/hip_runtime.h>
#include <hip/hip_bf16.h>
#include <stdint.h>

// Problem constants (T, B, N, D) = (4, 16, 1024, 512); M = B*N
#define T_ 4
#define M_ 16384
#define D_ 512
#define R_ (T_ * M_)   // 65536 rows total

// ---------------------------------------------------------------------------
// Kernel 1: fused Q/K/V projection (f64 accumulate) + LIF + attn = q*cumsum(k*v)
// Inputs are FLOAT32 (round-1 NaN proved they are not bf16 bit patterns).
// grid (D_/64, M_/4), block 256. Thread: dl = tid&63 -> one d; ml = tid>>6 -> one m.
// f64 is REQUIRED: spike = (mem >= 1.0) hard threshold; fp32 accumulation-order
// noise (~1e-6) vs the f64 numpy reference flips O(100) spikes; one flip moves
// the output by up to ~0.5 >> 0.0223 threshold. f64 leaves ~1e-14 margin.
// ---------------------------------------------------------------------------
__global__ __launch_bounds__(256) void proj_lif_attn_kernel(
    const float* __restrict__ X,    // (T*M, D) f32
    const float* __restrict__ Wq,   // (D, D) f32 (row d = output d)
    const float* __restrict__ Wk,
    const float* __restrict__ Wv,
    unsigned char* __restrict__ attn)  // (T*M, D) in {0..4}
{
    __shared__ float Xs[T_][4][64];   // 4 KB   (reads are wave-broadcast: free)
    __shared__ float Ws[3][64][68];   // 52.2 KB (stride 68 -> float4 rows 16B-aligned)

    const int tid = threadIdx.x;
    const int dl  = tid & 63;
    const int ml  = tid >> 6;
    const int bd  = blockIdx.x;   // 0..7
    const int bm  = blockIdx.y;   // 0..4095
    const int m   = bm * 4 + ml;
    const int d   = bd * 64 + dl;

    double acc[3][T_];
    #pragma unroll
    for (int z = 0; z < 3; z++)
        #pragma unroll
        for (int t = 0; t < T_; t++) acc[z][t] = 0.0;

    for (int kb = 0; kb < D_; kb += 64) {
        // stage X tile: 4t x 4m x 64k = 1024 floats, one float4 per thread
        {
            const int flat = tid * 4;
            const int t    = flat >> 8;
            const int mm   = (flat >> 6) & 3;
            const int k    = flat & 63;
            float4 v = *reinterpret_cast<const float4*>(
                X + ((size_t)(t * M_ + bm * 4 + mm) * D_ + kb + k));
            *reinterpret_cast<float4*>(&Xs[t][mm][k]) = v;
        }
        // stage W tiles: 3z x 64d x 64k = 12288 floats, 12 x float4 per thread
        #pragma unroll
        for (int i = 0; i < 12; i++) {
            const int flat = (tid + i * 256) * 4;
            const int z    = flat >> 12;
            const int rem  = flat & 4095;
            const int row  = rem >> 6;
            const int k    = rem & 63;
            const float* Wz = (z == 0) ? Wq : ((z == 1) ? Wk : Wv);
            float4 v = *reinterpret_cast<const float4*>(
                Wz + ((size_t)(bd * 64 + row) * D_ + kb + k));
            *reinterpret_cast<float4*>(&Ws[z][row][k]) = v;
        }
        __syncthreads();

        for (int k = 0; k < 64; k += 4) {
            double xd[T_][4];
            #pragma unroll
            for (int t = 0; t < T_; t++) {
                float4 xv = *reinterpret_cast<const float4*>(&Xs[t][ml][k]);  // broadcast
                xd[t][0] = (double)xv.x; xd[t][1] = (double)xv.y;
                xd[t][2] = (double)xv.z; xd[t][3] = (double)xv.w;
            }
            #pragma unroll
            for (int z = 0; z < 3; z++) {
                float4 wv = *reinterpret_cast<const float4*>(&Ws[z][dl][k]);
                const double w0 = (double)wv.x;
                const double w1 = (double)wv.y;
                const double w2 = (double)wv.z;
                const double w3 = (double)wv.w;
                #pragma unroll
                for (int t = 0; t < T_; t++) {
                    acc[z][t] += xd[t][0] * w0;
                    acc[z][t] += xd[t][1] * w1;
                    acc[z][t] += xd[t][2] * w2;
                    acc[z][t] += xd[t][3] * w3;
                }
            }
        }
        __syncthreads();
    }

    // LIF (f64, matches numpy f64 semantics): mem = 0.9*mem + pre; spike = mem>=1; mem -= spike
    int sp[3][T_];
    #pragma unroll
    for (int z = 0; z < 3; z++) {
        double mem = 0.0;
        #pragma unroll
        for (int t = 0; t < T_; t++) {
            mem = 0.9 * mem + acc[z][t];
            const int s = (mem >= 1.0) ? 1 : 0;
            sp[z][t] = s;
            mem -= (double)s;
        }
    }
    // attn[t] = q[t] * cumsum_t(k*v)  (exact small ints, <= 4)
    int ctx = 0;
    #pragma unroll
    for (int t = 0; t < T_; t++) {
        ctx += sp[1][t] & sp[2][t];
        attn[(size_t)(t * M_ + m) * D_ + d] = (unsigned char)(sp[0][t] ? ctx : 0);
    }
}

// ---------------------------------------------------------------------------
// Kernel 2: out = attn @ Wp^T + bp  (fp32 accumulate; inputs exact -> err ~1e-6)
// grid (D_/64, R_/16), block 256. Thread: one d, 4 rows.
// ---------------------------------------------------------------------------
__global__ __launch_bounds__(256) void attn_out_gemm_kernel(
    const unsigned char* __restrict__ A,    // (R, D) attn
    const float*         __restrict__ Wp,   // (D, D) f32
    const float*         __restrict__ bp,   // (D,)  f32
    float* __restrict__ out)                // (R, D) f32
{
    __shared__ unsigned char As[16][64];   // 1 KB
    __shared__ float         Ws2[64][68];  // 17.4 KB

    const int tid = threadIdx.x;
    const int dl  = tid & 63;
    const int rl  = tid >> 6;     // 0..3 -> rows rl*4 .. rl*4+3
    const int bd  = blockIdx.x;   // 0..7
    const int br  = blockIdx.y;   // 0..4095
    const int d   = bd * 64 + dl;

    float acc[4] = {0.f, 0.f, 0.f, 0.f};

    for (int kb = 0; kb < D_; kb += 64) {
        {
            const int flat = tid * 4;
            const int row  = flat >> 6;   // 0..15
            const int k    = flat & 63;
            *reinterpret_cast<uchar4*>(&As[row][k]) =
                *reinterpret_cast<const uchar4*>(A + (size_t)(br * 16 + row) * D_ + kb + k);
        }
        #pragma unroll
        for (int i = 0; i < 4; i++) {
            const int flat = (tid + i * 256) * 4;
            const int row  = flat >> 6;   // 0..63
            const int k    = flat & 63;
            *reinterpret_cast<float4*>(&Ws2[row][k]) =
                *reinterpret_cast<const float4*>(Wp + (size_t)(bd * 64 + row) * D_ + kb + k);
        }
        __syncthreads();

        for (int k = 0; k < 64; k += 4) {
            float4 wv = *reinterpret_cast<const float4*>(&Ws2[dl][k]);
            #pragma unroll
            for (int j = 0; j < 4; j++) {
                uchar4 av = *reinterpret_cast<const uchar4*>(&As[rl * 4 + j][k]);  // broadcast
                acc[j] += (float)av.x * wv.x;
                acc[j] += (float)av.y * wv.y;
                acc[j] += (float)av.z * wv.z;
                acc[j] += (float)av.w * wv.w;
            }
        }
        __syncthreads();
    }

    const float bias = bp[d];
    #pragma unroll
    for (int j = 0; j < 4; j++) {
        const int r = br * 16 + rl * 4 + j;
        out[(size_t)r * D_ + d] = acc[j] + bias;
    }
}

extern "C" void kernel_launch(void* const* d_in, const int* in_sizes, int n_in,
                              void* d_out, int out_size, void* d_ws, size_t ws_size,
                              hipStream_t stream) {
    const float* x  = (const float*)d_in[0];  // x_seq (T,B,N,D) f32
    const float* wq = (const float*)d_in[1];
    const float* wk = (const float*)d_in[2];
    const float* wv = (const float*)d_in[3];
    const float* wp = (const float*)d_in[4];
    const float* bp = (const float*)d_in[5];

    unsigned char* attn = (unsigned char*)d_ws;   // (T*M, D) = 33.5 MB scratch

    dim3 blk(256);
    dim3 g1(D_ / 64, M_ / 4);    // (8, 4096)
    proj_lif_attn_kernel<<<g1, blk, 0, stream>>>(x, wq, wk, wv, attn);

    dim3 g2(D_ / 64, R_ / 16);   // (8, 4096)
    attn_out_gemm_kernel<<<g2, blk, 0, stream>>>(attn, wp, bp, (float*)d_out);
}

// Round 4
// 3024.717 us; speedup vs baseline: 1.5910x; 1.5910x over previous
//
#include <hip/hip_runtime.h>
#include <hip/hip_bf16.h>
#include <stdint.h>

// Problem constants (T, B, N, D) = (4, 16, 1024, 512); M = B*N
#define T_ 4
#define M_ 16384
#define D_ 512
#define R_ (T_ * M_)   // 65536 rows total
#define BK 64
#define EPS_TRIG 1e-4f  // ~30 sigma of fp32 K=512 accumulation noise

// ---------------------------------------------------------------------------
// Kernel 1: fp32 projection + LIF with selective exact-f64 fixup.
// spike = (mem >= 1.0) must match a float64 reference; instead of computing
// everything in f64 (round 2: 4.43 ms, VALU-bound), compute fp32 and recompute
// exactly (f64, from global) only chains where any |mem-1| < 1e-4 (~3.6% of
// waves, masked). Round-3's f64 MFMA had an unverified fragment layout -> wrong
// results; this path reuses only the round-2-verified structure.
// LDS: W stored k-major (WsT[z][k][65]) -> inner W reads are b32 at bank
// (k+dl)%32 = 2 lanes/bank = free. Round-2's row-major stride-68 b128 reads
// were 8-way conflicted (4.2e8 conflict cycles measured).
// Thread: dl = tid&63 -> d; wv = tid>>6 -> m-pair {bm*8+2wv, +1}. 24 fp32 acc.
// ---------------------------------------------------------------------------
__global__ __launch_bounds__(256) void proj_lif_attn_f32fix(
    const float* __restrict__ X,    // (T*M, D) f32
    const float* __restrict__ Wq,   // (D, D) f32 (row d = output d)
    const float* __restrict__ Wk,
    const float* __restrict__ Wv,
    unsigned char* __restrict__ attn)  // (T*M, D) in {0..4}
{
    __shared__ float Xs[T_][8][BK];    // 8 KB   [t][m][k], reads are broadcast
    __shared__ float WsT[3][BK][65];   // 49.9 KB [z][k][d], pad 65 -> b32 conflict-free

    const int tid = threadIdx.x;
    const int dl  = tid & 63;
    const int wv  = tid >> 6;      // 0..3
    const int bd  = blockIdx.x;    // 0..7    (64 d per block)
    const int bm  = blockIdx.y;    // 0..2047 (8 m per block)
    const int d   = bd * 64 + dl;

    float acc[3][T_][2];
    #pragma unroll
    for (int z = 0; z < 3; z++)
        #pragma unroll
        for (int t = 0; t < T_; t++)
            acc[z][t][0] = acc[z][t][1] = 0.f;

    for (int kb = 0; kb < D_; kb += BK) {
        // stage X: 4t x 8m x 64k = 512 float4, 2 per thread
        #pragma unroll
        for (int i = 0; i < 2; i++) {
            const int j   = tid + i * 256;   // 0..511
            const int row = j >> 4;          // 0..31 = t*8+m
            const int t   = row >> 3;
            const int mm  = row & 7;
            const int kq  = (j & 15) * 4;
            float4 v = *reinterpret_cast<const float4*>(
                X + ((size_t)(t * M_ + bm * 8 + mm) * D_ + kb + kq));
            *reinterpret_cast<float4*>(&Xs[t][mm][kq]) = v;
        }
        // stage W transposed: 3z x 64d x 64k = 3072 float4, 12 per thread.
        // write banks: (kq+jj+row)%32 -> 2/bank = free.
        #pragma unroll
        for (int i = 0; i < 12; i++) {
            const int z   = i >> 2;                 // compile-time per unrolled i
            const int rem = tid + (i & 3) * 256;    // 0..1023
            const int row = rem >> 4;               // 0..63 (d within block)
            const int kq  = (rem & 15) * 4;
            const float* Wz = (z == 0) ? Wq : ((z == 1) ? Wk : Wv);
            float4 w = *reinterpret_cast<const float4*>(
                Wz + ((size_t)(bd * 64 + row) * D_ + kb + kq));
            WsT[z][kq + 0][row] = w.x;
            WsT[z][kq + 1][row] = w.y;
            WsT[z][kq + 2][row] = w.z;
            WsT[z][kq + 3][row] = w.w;
        }
        __syncthreads();

        #pragma unroll 4
        for (int kk = 0; kk < BK; kk += 4) {
            float4 xv[T_][2];
            #pragma unroll
            for (int t = 0; t < T_; t++)
                #pragma unroll
                for (int mi = 0; mi < 2; mi++)
                    xv[t][mi] = *reinterpret_cast<const float4*>(&Xs[t][wv * 2 + mi][kk]);
            #pragma unroll
            for (int j2 = 0; j2 < 4; j2++) {
                const float w0 = WsT[0][kk + j2][dl];
                const float w1 = WsT[1][kk + j2][dl];
                const float w2 = WsT[2][kk + j2][dl];
                #pragma unroll
                for (int t = 0; t < T_; t++)
                    #pragma unroll
                    for (int mi = 0; mi < 2; mi++) {
                        const float xx = (j2 == 0) ? xv[t][mi].x :
                                         (j2 == 1) ? xv[t][mi].y :
                                         (j2 == 2) ? xv[t][mi].z : xv[t][mi].w;
                        acc[0][t][mi] += xx * w0;
                        acc[1][t][mi] += xx * w1;
                        acc[2][t][mi] += xx * w2;
                    }
            }
        }
        __syncthreads();
    }

    // LIF in fp32 with exact-f64 fixup for near-threshold chains
    #pragma unroll
    for (int mi = 0; mi < 2; mi++) {
        const int m = bm * 8 + wv * 2 + mi;
        int sp[3][T_];
        #pragma unroll
        for (int z = 0; z < 3; z++) {
            float mem = 0.f;
            bool risky = false;
            #pragma unroll
            for (int t = 0; t < T_; t++) {
                mem = 0.9f * mem + acc[z][t][mi];
                risky |= (fabsf(mem - 1.0f) < EPS_TRIG);
                const int s = (mem >= 1.0f) ? 1 : 0;
                sp[z][t] = s;
                mem -= (float)s;
            }
            if (risky) {
                // exact recompute of this (z, m) chain in f64 from global
                const float* Wrow = ((z == 0) ? Wq : ((z == 1) ? Wk : Wv)) + (size_t)d * D_;
                double pre[T_];
                #pragma unroll
                for (int t = 0; t < T_; t++) {
                    const float* xrow = X + (size_t)(t * M_ + m) * D_;
                    double s0 = 0.0, s1 = 0.0, s2 = 0.0, s3 = 0.0;
                    for (int k = 0; k < D_; k += 4) {
                        s0 += (double)xrow[k + 0] * (double)Wrow[k + 0];
                        s1 += (double)xrow[k + 1] * (double)Wrow[k + 1];
                        s2 += (double)xrow[k + 2] * (double)Wrow[k + 2];
                        s3 += (double)xrow[k + 3] * (double)Wrow[k + 3];
                    }
                    pre[t] = (s0 + s1) + (s2 + s3);
                }
                double dm = 0.0;
                #pragma unroll
                for (int t = 0; t < T_; t++) {
                    dm = 0.9 * dm + pre[t];
                    const int s = (dm >= 1.0) ? 1 : 0;
                    sp[z][t] = s;
                    dm -= (double)s;
                }
            }
        }
        int ctx = 0;
        #pragma unroll
        for (int t = 0; t < T_; t++) {
            ctx += sp[1][t] & sp[2][t];
            attn[(size_t)(t * M_ + m) * D_ + d] = (unsigned char)(sp[0][t] ? ctx : 0);
        }
    }
}

// ---------------------------------------------------------------------------
// Kernel 2: out = attn @ Wp^T + bp  (fp32 accumulate; inputs exact -> err ~1e-6)
// grid (D_/64, R_/16), block 256. Thread: one d, 4 rows. (unchanged, known good)
// ---------------------------------------------------------------------------
__global__ __launch_bounds__(256) void attn_out_gemm_kernel(
    const unsigned char* __restrict__ A,    // (R, D) attn
    const float*         __restrict__ Wp,   // (D, D) f32
    const float*         __restrict__ bp,   // (D,)  f32
    float* __restrict__ out)                // (R, D) f32
{
    __shared__ unsigned char As[16][64];   // 1 KB
    __shared__ float         Ws2[64][68];  // 17.4 KB

    const int tid = threadIdx.x;
    const int dl  = tid & 63;
    const int rl  = tid >> 6;     // 0..3 -> rows rl*4 .. rl*4+3
    const int bd  = blockIdx.x;   // 0..7
    const int br  = blockIdx.y;   // 0..4095
    const int d   = bd * 64 + dl;

    float acc[4] = {0.f, 0.f, 0.f, 0.f};

    for (int kb = 0; kb < D_; kb += 64) {
        {
            const int flat = tid * 4;
            const int row  = flat >> 6;   // 0..15
            const int k    = flat & 63;
            *reinterpret_cast<uchar4*>(&As[row][k]) =
                *reinterpret_cast<const uchar4*>(A + (size_t)(br * 16 + row) * D_ + kb + k);
        }
        #pragma unroll
        for (int i = 0; i < 4; i++) {
            const int flat = (tid + i * 256) * 4;
            const int row  = flat >> 6;   // 0..63
            const int k    = flat & 63;
            *reinterpret_cast<float4*>(&Ws2[row][k]) =
                *reinterpret_cast<const float4*>(Wp + (size_t)(bd * 64 + row) * D_ + kb + k);
        }
        __syncthreads();

        for (int k = 0; k < 64; k += 4) {
            float4 wv = *reinterpret_cast<const float4*>(&Ws2[dl][k]);
            #pragma unroll
            for (int j = 0; j < 4; j++) {
                uchar4 av = *reinterpret_cast<const uchar4*>(&As[rl * 4 + j][k]);  // broadcast
                acc[j] += (float)av.x * wv.x;
                acc[j] += (float)av.y * wv.y;
                acc[j] += (float)av.z * wv.z;
                acc[j] += (float)av.w * wv.w;
            }
        }
        __syncthreads();
    }

    const float bias = bp[d];
    #pragma unroll
    for (int j = 0; j < 4; j++) {
        const int r = br * 16 + rl * 4 + j;
        out[(size_t)r * D_ + d] = acc[j] + bias;
    }
}

extern "C" void kernel_launch(void* const* d_in, const int* in_sizes, int n_in,
                              void* d_out, int out_size, void* d_ws, size_t ws_size,
                              hipStream_t stream) {
    const float* x  = (const float*)d_in[0];  // x_seq (T,B,N,D) f32
    const float* wq = (const float*)d_in[1];
    const float* wk = (const float*)d_in[2];
    const float* wv = (const float*)d_in[3];
    const float* wp = (const float*)d_in[4];
    const float* bp = (const float*)d_in[5];

    unsigned char* attn = (unsigned char*)d_ws;   // (T*M, D) = 33.5 MB scratch

    dim3 blk(256);
    dim3 g1(D_ / 64, M_ / 8);    // (8, 2048); x fastest -> 8 d-blocks share X in L2
    proj_lif_attn_f32fix<<<g1, blk, 0, stream>>>(x, wq, wk, wv, attn);

    dim3 g2(D_ / 64, R_ / 16);   // (8, 4096)
    attn_out_gemm_kernel<<<g2, blk, 0, stream>>>(attn, wp, bp, (float*)d_out);
}

// Round 5
// 2072.700 us; speedup vs baseline: 2.3218x; 1.4593x over previous
//
#include <hip/hip_runtime.h>
#include <hip/hip_bf16.h>
#include <stdint.h>

// Problem constants (T, B, N, D) = (4, 16, 1024, 512); M = B*N
#define T_ 4
#define M_ 16384
#define D_ 512
#define R_ (T_ * M_)    // 65536 rows total
#define EPS_TRIG 1e-4f  // ~5 sigma of the bf16-split accumulation noise

typedef short bf16x8 __attribute__((ext_vector_type(8)));   // 8 bf16 (4 VGPRs)
typedef float f32x4  __attribute__((ext_vector_type(4)));

// x = hi + lo + residual, |residual| <= 2^-17 |x|.
// hi: truncation (bit-chop); lo: RNE of the exact fp32 residual.
static __device__ __forceinline__ void split2bf16(float x, unsigned short& h, unsigned short& l) {
    unsigned int u = __float_as_uint(x);
    h = (unsigned short)(u >> 16);
    float r = x - __uint_as_float(u & 0xFFFF0000u);   // exact
    unsigned int v = __float_as_uint(r);
    l = (unsigned short)((v + 0x7FFFu + ((v >> 16) & 1u)) >> 16);
}

// ---------------------------------------------------------------------------
// Kernel 0: one-shot W split -> Wh, Wl in workspace (3 x 512 x 512 each).
// ---------------------------------------------------------------------------
__global__ __launch_bounds__(256) void split_w_kernel(
    const float* __restrict__ Wq, const float* __restrict__ Wk, const float* __restrict__ Wv,
    unsigned short* __restrict__ Wh, unsigned short* __restrict__ Wl)
{
    const int idx4 = blockIdx.x * 256 + threadIdx.x;  // float4 index, < 196608
    const int flat = idx4 * 4;
    const int z    = flat >> 18;                      // 262144 elements per matrix
    const int off  = flat & 262143;
    const float* src = (z == 0) ? Wq : (z == 1) ? Wk : Wv;
    float4 v = *reinterpret_cast<const float4*>(src + off);
    ushort4 h, l;
    split2bf16(v.x, h.x, l.x);
    split2bf16(v.y, h.y, l.y);
    split2bf16(v.z, h.z, l.z);
    split2bf16(v.w, h.w, l.w);
    *reinterpret_cast<ushort4*>(Wh + flat) = h;
    *reinterpret_cast<ushort4*>(Wl + flat) = l;
}

// ---------------------------------------------------------------------------
// Kernel 1: projection via bf16 MFMA (3-term hi/lo split) + LIF + fixup + attn.
//
// Numerics: spike = (mem >= 1.0) vs a float64 reference. Main pass uses
// mfma_f32_16x16x32_bf16 on split operands: xh*wh + xh*wl + xl*wh, noise
// sigma ~2e-5. Chains with any |mem-1| < 1e-4 (5 sigma) are recomputed
// exactly in f64 from the ORIGINAL f32 arrays (round-4-verified fixup).
//
// Verified MFMA layouts (m89/m91/m92): A[m=lane&15][k=(lane>>4)*8+j],
// B^T input with identical addressing (row n = lane&15), C/D col=lane&15,
// row=(lane>>4)*4+reg. Block: 4 waves; tile 32m x 64d; each wave: 16d
// (wsub), 2 m-subtiles, all 3 z and 4 t -> 24 f32x4 accumulators.
// LDS rows padded to 40 bf16 -> b128 frag reads = 8 words/bank (minimum).
// ---------------------------------------------------------------------------
__global__ __launch_bounds__(256) void proj_lif_attn_mfma(
    const float* __restrict__ X,
    const float* __restrict__ Wq, const float* __restrict__ Wk, const float* __restrict__ Wv,
    const unsigned short* __restrict__ WhS, const unsigned short* __restrict__ WlS,
    unsigned char* __restrict__ attn)
{
    __shared__ unsigned short XsH[128 * 40];   // [t*32+m][k]  10 KB
    __shared__ unsigned short XsL[128 * 40];   //              10 KB
    __shared__ unsigned short WsH[192 * 40];   // [z*64+dd][k] 15 KB
    __shared__ unsigned short WsL[192 * 40];   //              15 KB

    const int tid  = threadIdx.x;
    const int lane = tid & 63;
    const int wsub = tid >> 6;     // 0..3 -> 16-d subtile
    const int la   = lane & 15;
    const int lq   = lane >> 4;
    const int bd   = blockIdx.x;   // 0..7   (64 d per block)
    const int bm   = blockIdx.y;   // 0..511 (32 m per block)

    f32x4 acc[2][3][T_];
    #pragma unroll
    for (int s = 0; s < 2; s++)
        #pragma unroll
        for (int z = 0; z < 3; z++)
            #pragma unroll
            for (int t = 0; t < T_; t++)
                acc[s][z][t] = (f32x4){0.f, 0.f, 0.f, 0.f};

    for (int kb = 0; kb < D_; kb += 32) {
        // X stage: 4t x 32m x 32k f32 -> split -> hi/lo bf16 in LDS
        #pragma unroll
        for (int i = 0; i < 4; i++) {
            const int j   = tid + i * 256;  // 0..1023 float4 slots
            const int row = j >> 3;         // 0..127 = t*32+m
            const int kq  = (j & 7) * 4;
            const int t   = row >> 5;
            const int mm  = row & 31;
            float4 xv = *reinterpret_cast<const float4*>(
                X + ((size_t)(t * M_ + bm * 32 + mm) * D_ + kb + kq));
            ushort4 h, l;
            split2bf16(xv.x, h.x, l.x);
            split2bf16(xv.y, h.y, l.y);
            split2bf16(xv.z, h.z, l.z);
            split2bf16(xv.w, h.w, l.w);
            *reinterpret_cast<ushort4*>(&XsH[row * 40 + kq]) = h;
            *reinterpret_cast<ushort4*>(&XsL[row * 40 + kq]) = l;
        }
        // W stage: precomputed bf16 hi/lo, 3z x 64d x 32k each
        {
            const int wd  = tid >> 2;   // 0..63
            const int wkg = tid & 3;    // 0..3 -> k-group of 8
            #pragma unroll
            for (int z = 0; z < 3; z++) {
                const size_t goff = (size_t)(z * D_ + bd * 64 + wd) * D_ + kb + wkg * 8;
                int4 hv = *reinterpret_cast<const int4*>(WhS + goff);
                int4 lv = *reinterpret_cast<const int4*>(WlS + goff);
                *reinterpret_cast<int4*>(&WsH[(z * 64 + wd) * 40 + wkg * 8]) = hv;
                *reinterpret_cast<int4*>(&WsL[(z * 64 + wd) * 40 + wkg * 8]) = lv;
            }
        }
        __syncthreads();

        bf16x8 bh[3], bl[3];
        #pragma unroll
        for (int z = 0; z < 3; z++) {
            const int brow = (z * 64 + wsub * 16 + la) * 40 + lq * 8;
            bh[z] = *reinterpret_cast<const bf16x8*>(&WsH[brow]);
            bl[z] = *reinterpret_cast<const bf16x8*>(&WsL[brow]);
        }
        #pragma unroll
        for (int s = 0; s < 2; s++)
            #pragma unroll
            for (int t = 0; t < T_; t++) {
                const int arow = (t * 32 + s * 16 + la) * 40 + lq * 8;
                bf16x8 ah = *reinterpret_cast<const bf16x8*>(&XsH[arow]);
                bf16x8 al = *reinterpret_cast<const bf16x8*>(&XsL[arow]);
                #pragma unroll
                for (int z = 0; z < 3; z++) {
                    acc[s][z][t] = __builtin_amdgcn_mfma_f32_16x16x32_bf16(ah, bh[z], acc[s][z][t], 0, 0, 0);
                    acc[s][z][t] = __builtin_amdgcn_mfma_f32_16x16x32_bf16(ah, bl[z], acc[s][z][t], 0, 0, 0);
                    acc[s][z][t] = __builtin_amdgcn_mfma_f32_16x16x32_bf16(al, bh[z], acc[s][z][t], 0, 0, 0);
                }
            }
        __syncthreads();
    }

    // Epilogue: LIF (fp32 + exact-f64 fixup) + attn = q * cumsum(k & v)
    const int d = bd * 64 + wsub * 16 + la;
    #pragma unroll
    for (int s = 0; s < 2; s++)
        #pragma unroll
        for (int i = 0; i < 4; i++) {
            const int m = bm * 32 + s * 16 + lq * 4 + i;
            int sp[3][T_];
            #pragma unroll
            for (int z = 0; z < 3; z++) {
                float mem = 0.f;
                bool risky = false;
                #pragma unroll
                for (int t = 0; t < T_; t++) {
                    mem = 0.9f * mem + acc[s][z][t][i];
                    risky |= (fabsf(mem - 1.0f) < EPS_TRIG);
                    const int sb = (mem >= 1.0f) ? 1 : 0;
                    sp[z][t] = sb;
                    mem -= (float)sb;
                }
                if (risky) {
                    const float* Wrow = ((z == 0) ? Wq : ((z == 1) ? Wk : Wv)) + (size_t)d * D_;
                    double pre[T_];
                    #pragma unroll
                    for (int t = 0; t < T_; t++) {
                        const float* xrow = X + (size_t)(t * M_ + m) * D_;
                        double s0 = 0.0, s1 = 0.0, s2 = 0.0, s3 = 0.0;
                        for (int k = 0; k < D_; k += 4) {
                            s0 += (double)xrow[k + 0] * (double)Wrow[k + 0];
                            s1 += (double)xrow[k + 1] * (double)Wrow[k + 1];
                            s2 += (double)xrow[k + 2] * (double)Wrow[k + 2];
                            s3 += (double)xrow[k + 3] * (double)Wrow[k + 3];
                        }
                        pre[t] = (s0 + s1) + (s2 + s3);
                    }
                    double dm = 0.0;
                    #pragma unroll
                    for (int t = 0; t < T_; t++) {
                        dm = 0.9 * dm + pre[t];
                        const int sb = (dm >= 1.0) ? 1 : 0;
                        sp[z][t] = sb;
                        dm -= (double)sb;
                    }
                }
            }
            int ctx = 0;
            #pragma unroll
            for (int t = 0; t < T_; t++) {
                ctx += sp[1][t] & sp[2][t];
                attn[(size_t)(t * M_ + m) * D_ + d] = (unsigned char)(sp[0][t] ? ctx : 0);
            }
        }
}

// ---------------------------------------------------------------------------
// Kernel 2: out = attn @ Wp^T + bp  (fp32 accumulate; unchanged, known good)
// ---------------------------------------------------------------------------
__global__ __launch_bounds__(256) void attn_out_gemm_kernel(
    const unsigned char* __restrict__ A,    // (R, D) attn
    const float*         __restrict__ Wp,   // (D, D) f32
    const float*         __restrict__ bp,   // (D,)  f32
    float* __restrict__ out)                // (R, D) f32
{
    __shared__ unsigned char As[16][64];   // 1 KB
    __shared__ float         Ws2[64][68];  // 17.4 KB

    const int tid = threadIdx.x;
    const int dl  = tid & 63;
    const int rl  = tid >> 6;
    const int bd  = blockIdx.x;
    const int br  = blockIdx.y;
    const int d   = bd * 64 + dl;

    float acc[4] = {0.f, 0.f, 0.f, 0.f};

    for (int kb = 0; kb < D_; kb += 64) {
        {
            const int flat = tid * 4;
            const int row  = flat >> 6;
            const int k    = flat & 63;
            *reinterpret_cast<uchar4*>(&As[row][k]) =
                *reinterpret_cast<const uchar4*>(A + (size_t)(br * 16 + row) * D_ + kb + k);
        }
        #pragma unroll
        for (int i = 0; i < 4; i++) {
            const int flat = (tid + i * 256) * 4;
            const int row  = flat >> 6;
            const int k    = flat & 63;
            *reinterpret_cast<float4*>(&Ws2[row][k]) =
                *reinterpret_cast<const float4*>(Wp + (size_t)(bd * 64 + row) * D_ + kb + k);
        }
        __syncthreads();

        for (int k = 0; k < 64; k += 4) {
            float4 wv = *reinterpret_cast<const float4*>(&Ws2[dl][k]);
            #pragma unroll
            for (int j = 0; j < 4; j++) {
                uchar4 av = *reinterpret_cast<const uchar4*>(&As[rl * 4 + j][k]);
                acc[j] += (float)av.x * wv.x;
                acc[j] += (float)av.y * wv.y;
                acc[j] += (float)av.z * wv.z;
                acc[j] += (float)av.w * wv.w;
            }
        }
        __syncthreads();
    }

    const float bias = bp[d];
    #pragma unroll
    for (int j = 0; j < 4; j++) {
        const int r = br * 16 + rl * 4 + j;
        out[(size_t)r * D_ + d] = acc[j] + bias;
    }
}

extern "C" void kernel_launch(void* const* d_in, const int* in_sizes, int n_in,
                              void* d_out, int out_size, void* d_ws, size_t ws_size,
                              hipStream_t stream) {
    const float* x  = (const float*)d_in[0];  // x_seq (T,B,N,D) f32
    const float* wq = (const float*)d_in[1];
    const float* wk = (const float*)d_in[2];
    const float* wv = (const float*)d_in[3];
    const float* wp = (const float*)d_in[4];
    const float* bp = (const float*)d_in[5];

    // workspace layout: attn 33.5 MB | Wh 1.5 MB | Wl 1.5 MB  (total ~36.7 MB)
    unsigned char*  attn = (unsigned char*)d_ws;
    unsigned short* Wh   = (unsigned short*)((char*)d_ws + 33554432);
    unsigned short* Wl   = (unsigned short*)((char*)d_ws + 33554432 + 1572864);

    dim3 blk(256);
    split_w_kernel<<<dim3(768), blk, 0, stream>>>(wq, wk, wv, Wh, Wl);

    dim3 g1(D_ / 64, M_ / 32);   // (8, 512); bd fastest -> 8 d-blocks share X in L2/L3
    proj_lif_attn_mfma<<<g1, blk, 0, stream>>>(x, wq, wk, wv, Wh, Wl, attn);

    dim3 g2(D_ / 64, R_ / 16);   // (8, 4096)
    attn_out_gemm_kernel<<<g2, blk, 0, stream>>>(attn, wp, bp, (float*)d_out);
}